// Round 1
// baseline (356.788 us; speedup 1.0000x reference)
//
#include <hip/hip_runtime.h>

// ---------------------------------------------------------------------------
// GlimpseNetwork forward, fp32 end-to-end.
// B=512, C=1, H=W=256, NG=4, NP=3, GH=GW=16, SF=2, H_G=256, H_L=128, FLAT=1600
// d_out layout (floats): phi_out[512*256] | g_t[512*384] | bboxes[512*12*4]
// ws layout (floats):
//   phi  @ 0         (512*12*256 = 1,572,864)   [dead after conv1]
//   h1   @ 1,572,864 (512*32*49  =   802,816)   [dead after conv2]
//   h2   @ 0         (512*1600   =   819,200)   reuses phi region
//   part @ 1,572,864 (4*512*256  =   524,288)   reuses h1 region
//   lout @ 2,097,152 (512*128    =    65,536)
// peak ws = 2,375,680 floats = 9.5 MB
// ---------------------------------------------------------------------------

#define PHI_OUT_OFF 0
#define GT_OFF      131072
#define BBOX_OFF    327680

// ---- Kernel 1: foveation (patch extract + avg-pool pyramid) ---------------
// grid 512*12 blocks, 256 threads; block = (b, j*3+i)
__global__ __launch_bounds__(256) void foveate_kernel(
    const float* __restrict__ x,     // [512,1,256,256]
    const float* __restrict__ l,     // [512,4,2]
    float* __restrict__ phi,         // [512,12,16,16]
    float* __restrict__ bbox)        // [512,12,4]
{
    int blk = blockIdx.x;
    int b  = blk / 12;
    int ji = blk % 12;
    int j  = ji / 3;
    int i  = ji % 3;
    int gh   = 16 << i;       // 16, 32, 64
    int half = gh >> 1;
    int kh   = 1 << i;        // pool factor 1, 2, 4

    float l0 = l[(b * 4 + j) * 2 + 0];
    float l1 = l[(b * 4 + j) * 2 + 1];
    // match reference: trunc-toward-zero, then clamp to [0, 256-gh]
    int sx = (int)(0.5f * ((l0 + 1.0f) * 255.0f) - (float)half);
    int sy = (int)(0.5f * ((l1 + 1.0f) * 255.0f) - (float)half);
    sx = min(max(sx, 0), 256 - gh);
    sy = min(max(sy, 0), 256 - gh);

    int t = threadIdx.x;           // output pixel: r = t/16, c = t%16
    int r = t >> 4, c = t & 15;
    const float* xb = x + (size_t)b * 65536;
    int row0 = sx + r * kh;
    int col0 = sy + c * kh;
    float s = 0.0f;
    for (int dy = 0; dy < kh; ++dy) {
        const float* xr = xb + (row0 + dy) * 256 + col0;
        for (int dx = 0; dx < kh; ++dx) s += xr[dx];
    }
    s *= (1.0f / (float)(kh * kh));
    phi[((size_t)b * 12 + ji) * 256 + t] = s;

    if (t == 0) {
        float* bb = bbox + ((size_t)b * 12 + ji) * 4;
        bb[0] = (float)sy;
        bb[1] = (float)sx;
        bb[2] = (float)(sy + gh);
        bb[3] = (float)(sx + gh);
    }
}

// ---- Kernel 2: conv1 12->32, k4 s2, VALID, +bias, ReLU --------------------
// grid 512 blocks (one per image), 256 threads
__global__ __launch_bounds__(256) void conv1_kernel(
    const float* __restrict__ phi,   // [512,12,16,16]
    const float* __restrict__ w,     // [32,12,4,4]
    const float* __restrict__ bias,  // [32]
    float* __restrict__ out)         // [512,32,7,7]
{
    __shared__ float in_s[3072];   // 12*16*16
    __shared__ float w_s[6144];    // 32*12*4*4
    int b = blockIdx.x;
    int t = threadIdx.x;
    const float* pin = phi + (size_t)b * 3072;
    for (int k = t; k < 3072; k += 256) in_s[k] = pin[k];
    for (int k = t; k < 6144; k += 256) w_s[k] = w[k];
    __syncthreads();
    for (int oi = t; oi < 1568; oi += 256) {   // 32*49 outputs
        int oc = oi / 49;
        int p  = oi % 49;
        int py = p / 7, px = p % 7;
        float acc = bias[oc];
        const float* wp = w_s + oc * 192;
        const float* ip = in_s + (2 * py) * 16 + 2 * px;
        for (int c = 0; c < 12; ++c) {
            const float* ic = ip + c * 256;
            const float* wc = wp + c * 16;
            #pragma unroll
            for (int ky = 0; ky < 4; ++ky) {
                #pragma unroll
                for (int kx = 0; kx < 4; ++kx)
                    acc += ic[ky * 16 + kx] * wc[ky * 4 + kx];
            }
        }
        out[(size_t)b * 1568 + oi] = fmaxf(acc, 0.0f);
    }
}

// ---- Kernel 3: conv2 32->64, k3 s1, VALID, +bias, ReLU --------------------
// grid 512 blocks, 256 threads; LDS = 80 KB -> 2 blocks/CU
__global__ __launch_bounds__(256) void conv2_kernel(
    const float* __restrict__ h1,    // [512,32,7,7]
    const float* __restrict__ w,     // [64,32,3,3]
    const float* __restrict__ bias,  // [64]
    float* __restrict__ out)         // [512,64,5,5] == [512,1600] flat
{
    __shared__ float in_s[1568];     // 32*7*7
    __shared__ float w_s[18432];     // 64*32*3*3
    int b = blockIdx.x;
    int t = threadIdx.x;
    const float* pin = h1 + (size_t)b * 1568;
    for (int k = t; k < 1568; k += 256) in_s[k] = pin[k];
    for (int k = t; k < 18432; k += 256) w_s[k] = w[k];
    __syncthreads();
    for (int oi = t; oi < 1600; oi += 256) {   // 64*25 outputs
        int oc = oi / 25;
        int p  = oi % 25;
        int py = p / 5, px = p % 5;
        float acc = bias[oc];
        const float* wp = w_s + oc * 288;
        for (int c = 0; c < 32; ++c) {
            const float* ic = in_s + c * 49 + py * 7 + px;
            const float* wc = wp + c * 9;
            acc += ic[0]  * wc[0] + ic[1]  * wc[1] + ic[2]  * wc[2]
                 + ic[7]  * wc[3] + ic[8]  * wc[4] + ic[9]  * wc[5]
                 + ic[14] * wc[6] + ic[15] * wc[7] + ic[16] * wc[8];
        }
        out[(size_t)b * 1600 + oi] = fmaxf(acc, 0.0f);
    }
}

// ---- Kernel 4: fc1 partial GEMM, K split into 4 chunks of 400 -------------
// grid (64 batch-tiles, 4 k-chunks), 256 threads = 256 out channels, NB=8
__global__ __launch_bounds__(256) void fc1_partial_kernel(
    const float* __restrict__ h2,      // [512,1600]
    const float* __restrict__ w,       // [256,1600]
    float* __restrict__ partial)       // [4,512,256]
{
    __shared__ float in_s[8 * 400];
    int bt = blockIdx.x;   // batch tile: b = bt*8 + bb
    int kc = blockIdx.y;   // k chunk
    int t  = threadIdx.x;  // out channel
    int k0 = kc * 400;
    for (int idx = t; idx < 8 * 400; idx += 256) {
        int bb = idx / 400, kk = idx % 400;
        in_s[idx] = h2[(size_t)(bt * 8 + bb) * 1600 + k0 + kk];
    }
    __syncthreads();
    float acc[8] = {0.f, 0.f, 0.f, 0.f, 0.f, 0.f, 0.f, 0.f};
    const float4* wp = (const float4*)(w + (size_t)t * 1600 + k0);
    for (int k4 = 0; k4 < 100; ++k4) {
        float4 wv = wp[k4];
        int k = k4 * 4;
        #pragma unroll
        for (int bb = 0; bb < 8; ++bb) {
            float4 iv = *(const float4*)&in_s[bb * 400 + k];
            acc[bb] += wv.x * iv.x + wv.y * iv.y + wv.z * iv.z + wv.w * iv.w;
        }
    }
    float* pp = partial + ((size_t)kc * 512 + bt * 8) * 256 + t;
    #pragma unroll
    for (int bb = 0; bb < 8; ++bb) pp[bb * 256] = acc[bb];
}

// ---- Kernel 5: fc1 reduce + bias + ReLU -> phi_out;  fc2 -> l_out ---------
// grid 512 blocks (one per b), 256 threads
__global__ __launch_bounds__(256) void fc12_finish_kernel(
    const float* __restrict__ partial,  // [4,512,256]
    const float* __restrict__ fc1_b,    // [256]
    const float* __restrict__ l,        // [512,8]
    const float* __restrict__ fc2_w,    // [128,8]
    const float* __restrict__ fc2_b,    // [128]
    float* __restrict__ phi_out,        // [512,256]
    float* __restrict__ l_out)          // [512,128]
{
    int b = blockIdx.x, t = threadIdx.x;
    size_t idx = (size_t)b * 256 + t;
    float s = fc1_b[t];
    #pragma unroll
    for (int kc = 0; kc < 4; ++kc) s += partial[(size_t)kc * 131072 + idx];
    phi_out[idx] = fmaxf(s, 0.0f);
    if (t < 128) {
        float a = fc2_b[t];
        const float* lb = l + b * 8;
        const float* wr = fc2_w + t * 8;
        #pragma unroll
        for (int m = 0; m < 8; ++m) a += lb[m] * wr[m];
        l_out[b * 128 + t] = fmaxf(a, 0.0f);
    }
}

// ---- Kernel 6: g_t = relu(phi_out@fc3^T + fc3_b + l_out@fc4^T + fc4_b) ----
// grid 128 blocks (4 b each), 384 threads = 384 out channels
__global__ __launch_bounds__(384) void gt_kernel(
    const float* __restrict__ phi_out,  // [512,256]
    const float* __restrict__ l_out,    // [512,128]
    const float* __restrict__ fc3_w,    // [384,256]
    const float* __restrict__ fc3_b,    // [384]
    const float* __restrict__ fc4_w,    // [384,128]
    const float* __restrict__ fc4_b,    // [384]
    float* __restrict__ g_t)            // [512,384]
{
    __shared__ float ph_s[4 * 256];
    __shared__ float lo_s[4 * 128];
    int bt = blockIdx.x;   // b = bt*4 + bb
    int t  = threadIdx.x;  // out channel
    for (int i = t; i < 1024; i += 384) ph_s[i] = phi_out[(size_t)bt * 1024 + i];
    for (int i = t; i < 512;  i += 384) lo_s[i] = l_out[(size_t)bt * 512 + i];
    __syncthreads();
    float base = fc3_b[t] + fc4_b[t];
    float acc[4] = {base, base, base, base};
    const float4* w3 = (const float4*)(fc3_w + (size_t)t * 256);
    for (int k4 = 0; k4 < 64; ++k4) {
        float4 wv = w3[k4];
        int k = k4 * 4;
        #pragma unroll
        for (int bb = 0; bb < 4; ++bb) {
            float4 iv = *(const float4*)&ph_s[bb * 256 + k];
            acc[bb] += wv.x * iv.x + wv.y * iv.y + wv.z * iv.z + wv.w * iv.w;
        }
    }
    const float4* w4 = (const float4*)(fc4_w + (size_t)t * 128);
    for (int k4 = 0; k4 < 32; ++k4) {
        float4 wv = w4[k4];
        int k = k4 * 4;
        #pragma unroll
        for (int bb = 0; bb < 4; ++bb) {
            float4 iv = *(const float4*)&lo_s[bb * 128 + k];
            acc[bb] += wv.x * iv.x + wv.y * iv.y + wv.z * iv.z + wv.w * iv.w;
        }
    }
    #pragma unroll
    for (int bb = 0; bb < 4; ++bb)
        g_t[((size_t)bt * 4 + bb) * 384 + t] = fmaxf(acc[bb], 0.0f);
}

extern "C" void kernel_launch(void* const* d_in, const int* in_sizes, int n_in,
                              void* d_out, int out_size, void* d_ws, size_t ws_size,
                              hipStream_t stream) {
    const float* x   = (const float*)d_in[0];
    const float* l   = (const float*)d_in[1];
    const float* c1w = (const float*)d_in[2];
    const float* c1b = (const float*)d_in[3];
    const float* c2w = (const float*)d_in[4];
    const float* c2b = (const float*)d_in[5];
    const float* f1w = (const float*)d_in[6];
    const float* f1b = (const float*)d_in[7];
    const float* f2w = (const float*)d_in[8];
    const float* f2b = (const float*)d_in[9];
    const float* f3w = (const float*)d_in[10];
    const float* f3b = (const float*)d_in[11];
    const float* f4w = (const float*)d_in[12];
    const float* f4b = (const float*)d_in[13];

    float* out       = (float*)d_out;
    float* phi_out_p = out + PHI_OUT_OFF;
    float* gt_p      = out + GT_OFF;
    float* bbox_p    = out + BBOX_OFF;

    float* ws      = (float*)d_ws;
    float* phi     = ws;                 // [512,12,256]
    float* h1      = ws + 1572864;       // [512,32,49]
    float* h2      = ws;                 // [512,1600]  (reuses phi region)
    float* partial = ws + 1572864;       // [4,512,256] (reuses h1 region)
    float* l_out   = ws + 2097152;       // [512,128]

    foveate_kernel<<<6144, 256, 0, stream>>>(x, l, phi, bbox_p);
    conv1_kernel<<<512, 256, 0, stream>>>(phi, c1w, c1b, h1);
    conv2_kernel<<<512, 256, 0, stream>>>(h1, c2w, c2b, h2);
    fc1_partial_kernel<<<dim3(64, 4), 256, 0, stream>>>(h2, f1w, partial);
    fc12_finish_kernel<<<512, 256, 0, stream>>>(partial, f1b, l, f2w, f2b,
                                                phi_out_p, l_out);
    gt_kernel<<<128, 384, 0, stream>>>(phi_out_p, l_out, f3w, f3b, f4w, f4b, gt_p);
}

// Round 3
// 297.039 us; speedup vs baseline: 1.2011x; 1.2011x over previous
//
#include <hip/hip_runtime.h>

// ---------------------------------------------------------------------------
// GlimpseNetwork forward, fp32 end-to-end. Round 3 = Round 2 with the
// workspace aliasing fix: w_t moved PAST h1's region (it was inside it, so
// conv1 clobbered the repacked conv2 weights -> absmax 80 on phi_out).
//
// d_out layout (floats): phi_out[512*256] | g_t[512*384] | bboxes[512*12*4]
// ws layout (floats):
//   phi  [0,        1572864)  written foveate, read conv1 (dead after)
//   h1   [1572864,  2375680)  written conv1, read conv2   (dead after)
//   h2   [0,         819200)  written conv2 (over dead phi), read fc1
//   part [1572864,  2097152)  written fc1 (over dead h1), read fc12
//   lout [2097152,  2162688)  written fc12 (h1 dead), read gt
//   w_t  [2375680,  2394112)  written repack FIRST; nothing overlaps it now
// ---------------------------------------------------------------------------

#define PHI_OUT_OFF 0
#define GT_OFF      131072
#define BBOX_OFF    327680

#define WS_PHI   0
#define WS_H1    1572864
#define WS_H2    0
#define WS_PART  1572864
#define WS_LOUT  2097152
#define WS_WT    2375680   // FIXED: was 2162688, inside h1 [1572864,2375680)

// ---- Kernel 0: repack conv2 weights [64,32,3,3] -> [c*9+ky*3+kx][64] ------
__global__ __launch_bounds__(256) void repack_w2_kernel(
    const float* __restrict__ w, float* __restrict__ w_t)
{
    int idx = blockIdx.x * 256 + threadIdx.x;
    if (idx < 18432) {
        int oc = idx / 288, r = idx % 288;   // r = c*9 + ky*3 + kx
        w_t[r * 64 + oc] = w[idx];
    }
}

// ---- Kernel 1: foveation (patch extract + avg-pool pyramid) ---------------
__global__ __launch_bounds__(256) void foveate_kernel(
    const float* __restrict__ x,     // [512,1,256,256]
    const float* __restrict__ l,     // [512,4,2]
    float* __restrict__ phi,         // [512,12,16,16]
    float* __restrict__ bbox)        // [512,12,4]
{
    int blk = blockIdx.x;
    int b  = blk / 12;
    int ji = blk % 12;
    int j  = ji / 3;
    int i  = ji % 3;
    int gh   = 16 << i;
    int half = gh >> 1;
    int kh   = 1 << i;

    float l0 = l[(b * 4 + j) * 2 + 0];
    float l1 = l[(b * 4 + j) * 2 + 1];
    int sx = (int)(0.5f * ((l0 + 1.0f) * 255.0f) - (float)half);
    int sy = (int)(0.5f * ((l1 + 1.0f) * 255.0f) - (float)half);
    sx = min(max(sx, 0), 256 - gh);
    sy = min(max(sy, 0), 256 - gh);

    int t = threadIdx.x;
    int r = t >> 4, c = t & 15;
    const float* xb = x + (size_t)b * 65536;
    int row0 = sx + r * kh;
    int col0 = sy + c * kh;
    float s = 0.0f;
    for (int dy = 0; dy < kh; ++dy) {
        const float* xr = xb + (row0 + dy) * 256 + col0;
        for (int dx = 0; dx < kh; ++dx) s += xr[dx];
    }
    s *= (1.0f / (float)(kh * kh));
    phi[((size_t)b * 12 + ji) * 256 + t] = s;

    if (t == 0) {
        float* bb = bbox + ((size_t)b * 12 + ji) * 4;
        bb[0] = (float)sy;
        bb[1] = (float)sx;
        bb[2] = (float)(sy + gh);
        bb[3] = (float)(sx + gh);
    }
}

// ---- Kernel 2: conv1 12->32, k4 s2, +bias, ReLU ---------------------------
// 512 blocks (1 image), 128 threads (112 active): t = py*16 + oc2
// thread computes 2 oc x 7 px for one output row py.
__global__ __launch_bounds__(128) void conv1_kernel(
    const float* __restrict__ phi,   // [512,12,16,16]
    const float* __restrict__ w,     // [32,12,4,4]
    const float* __restrict__ bias,  // [32]
    float* __restrict__ out)         // [512,32,7,7]
{
    __shared__ float in_s[12 * 16 * 20];   // rows padded 16->20
    int b = blockIdx.x, t = threadIdx.x;
    const float* pin = phi + (size_t)b * 3072;
    for (int k = t; k < 3072; k += 128) {
        int c = k >> 8, q = k & 255, row = q >> 4, col = q & 15;
        in_s[(c * 16 + row) * 20 + col] = pin[k];
    }
    __syncthreads();
    if (t >= 112) return;
    int py = t >> 4, oc2 = t & 15, oc = oc2 * 2;

    float a0[7] = {0.f,0.f,0.f,0.f,0.f,0.f,0.f};
    float a1[7] = {0.f,0.f,0.f,0.f,0.f,0.f,0.f};
    for (int c = 0; c < 12; ++c) {
        for (int ky = 0; ky < 4; ++ky) {
            const float* rp = in_s + (c * 16 + 2 * py + ky) * 20;
            float4 r0 = *(const float4*)(rp);
            float4 r1 = *(const float4*)(rp + 4);
            float4 r2 = *(const float4*)(rp + 8);
            float4 r3 = *(const float4*)(rp + 12);
            float row[16] = {r0.x,r0.y,r0.z,r0.w, r1.x,r1.y,r1.z,r1.w,
                             r2.x,r2.y,r2.z,r2.w, r3.x,r3.y,r3.z,r3.w};
            float4 wa = *(const float4*)(w + (( oc      * 12 + c) * 4 + ky) * 4);
            float4 wb = *(const float4*)(w + (((oc + 1) * 12 + c) * 4 + ky) * 4);
            #pragma unroll
            for (int px = 0; px < 7; ++px) {
                int s2 = 2 * px;
                a0[px] += row[s2]*wa.x + row[s2+1]*wa.y + row[s2+2]*wa.z + row[s2+3]*wa.w;
                a1[px] += row[s2]*wb.x + row[s2+1]*wb.y + row[s2+2]*wb.z + row[s2+3]*wb.w;
            }
        }
    }
    float b0 = bias[oc], b1 = bias[oc + 1];
    float* o = out + (size_t)b * 1568 + oc * 49 + py * 7;
    #pragma unroll
    for (int px = 0; px < 7; ++px) {
        o[px]      = fmaxf(a0[px] + b0, 0.0f);
        o[px + 49] = fmaxf(a1[px] + b1, 0.0f);
    }
}

// ---- Kernel 3: conv2 32->64, k3 s1, +bias, ReLU ---------------------------
// 512 blocks (1 image), 192 threads (160 active): t = py*32 + oc2
// thread computes 2 oc x 5 px for one output row py. Weights from w_t (global).
__global__ __launch_bounds__(192) void conv2_kernel(
    const float* __restrict__ h1,    // [512,32,7,7]
    const float* __restrict__ w_t,   // [288,64]
    const float* __restrict__ bias,  // [64]
    float* __restrict__ out)         // [512,1600]
{
    __shared__ float in_s[32 * 7 * 8];   // rows padded 7->8
    int b = blockIdx.x, t = threadIdx.x;
    const float* pin = h1 + (size_t)b * 1568;
    for (int k = t; k < 1568; k += 192) {
        int c = k / 49, q = k % 49, row = q / 7, col = q % 7;
        in_s[c * 56 + row * 8 + col] = pin[k];
    }
    __syncthreads();
    if (t >= 160) return;
    int py = t >> 5, oc2 = t & 31, oc = oc2 * 2;

    float a0[5] = {0.f,0.f,0.f,0.f,0.f};
    float a1[5] = {0.f,0.f,0.f,0.f,0.f};
    for (int c = 0; c < 32; ++c) {
        #pragma unroll
        for (int ky = 0; ky < 3; ++ky) {
            const float* rp = in_s + c * 56 + (py + ky) * 8;
            float4 q0 = *(const float4*)(rp);
            float4 q1 = *(const float4*)(rp + 4);
            float row[8] = {q0.x,q0.y,q0.z,q0.w, q1.x,q1.y,q1.z,q1.w};
            #pragma unroll
            for (int kx = 0; kx < 3; ++kx) {
                float2 wv = *(const float2*)(w_t + (c * 9 + ky * 3 + kx) * 64 + oc);
                #pragma unroll
                for (int px = 0; px < 5; ++px) {
                    a0[px] += row[px + kx] * wv.x;
                    a1[px] += row[px + kx] * wv.y;
                }
            }
        }
    }
    float b0 = bias[oc], b1 = bias[oc + 1];
    float* o = out + (size_t)b * 1600 + oc * 25 + py * 5;
    #pragma unroll
    for (int px = 0; px < 5; ++px) {
        o[px]      = fmaxf(a0[px] + b0, 0.0f);
        o[px + 25] = fmaxf(a1[px] + b1, 0.0f);
    }
}

// ---- Kernel 4: fc1 partial GEMM; inputs wave-uniform (scalar-load path) ---
__global__ __launch_bounds__(256) void fc1_partial_kernel(
    const float* __restrict__ h2,      // [512,1600]
    const float* __restrict__ w,       // [256,1600]
    float* __restrict__ partial)       // [4,512,256]
{
    int bt = blockIdx.x, kc = blockIdx.y, t = threadIdx.x;
    const float4* wp = (const float4*)(w + (size_t)t * 1600 + kc * 400);
    const float*  hb = h2 + (size_t)bt * 8 * 1600 + kc * 400;   // uniform
    float acc[8] = {0.f,0.f,0.f,0.f,0.f,0.f,0.f,0.f};
    for (int k4 = 0; k4 < 100; ++k4) {
        float4 wv = wp[k4];
        #pragma unroll
        for (int bb = 0; bb < 8; ++bb) {
            float4 iv = *(const float4*)(hb + bb * 1600 + k4 * 4);  // uniform
            acc[bb] += wv.x*iv.x + wv.y*iv.y + wv.z*iv.z + wv.w*iv.w;
        }
    }
    float* pp = partial + ((size_t)kc * 512 + bt * 8) * 256 + t;
    #pragma unroll
    for (int bb = 0; bb < 8; ++bb) pp[bb * 256] = acc[bb];
}

// ---- Kernel 5: fc1 reduce + bias + ReLU -> phi_out;  fc2 -> l_out ---------
__global__ __launch_bounds__(256) void fc12_finish_kernel(
    const float* __restrict__ partial,  // [4,512,256]
    const float* __restrict__ fc1_b,    // [256]
    const float* __restrict__ l,        // [512,8]
    const float* __restrict__ fc2_w,    // [128,8]
    const float* __restrict__ fc2_b,    // [128]
    float* __restrict__ phi_out,        // [512,256]
    float* __restrict__ l_out)          // [512,128]
{
    int b = blockIdx.x, t = threadIdx.x;
    size_t idx = (size_t)b * 256 + t;
    float s = fc1_b[t];
    #pragma unroll
    for (int kc = 0; kc < 4; ++kc) s += partial[(size_t)kc * 131072 + idx];
    phi_out[idx] = fmaxf(s, 0.0f);
    if (t < 128) {
        float a = fc2_b[t];
        const float* lb = l + b * 8;
        const float* wr = fc2_w + t * 8;
        #pragma unroll
        for (int m = 0; m < 8; ++m) a += lb[m] * wr[m];
        l_out[b * 128 + t] = fmaxf(a, 0.0f);
    }
}

// ---- Kernel 6: g_t; inputs wave-uniform, weights per-thread streams -------
__global__ __launch_bounds__(384) void gt_kernel(
    const float* __restrict__ phi_out,  // [512,256]
    const float* __restrict__ l_out,    // [512,128]
    const float* __restrict__ fc3_w,    // [384,256]
    const float* __restrict__ fc3_b,    // [384]
    const float* __restrict__ fc4_w,    // [384,128]
    const float* __restrict__ fc4_b,    // [384]
    float* __restrict__ g_t)            // [512,384]
{
    int bt = blockIdx.x, t = threadIdx.x;
    float base = fc3_b[t] + fc4_b[t];
    float acc[4] = {base, base, base, base};
    const float4* w3 = (const float4*)(fc3_w + (size_t)t * 256);
    const float*  ph = phi_out + (size_t)bt * 4 * 256;   // uniform
    for (int k4 = 0; k4 < 64; ++k4) {
        float4 wv = w3[k4];
        #pragma unroll
        for (int bb = 0; bb < 4; ++bb) {
            float4 iv = *(const float4*)(ph + bb * 256 + k4 * 4);
            acc[bb] += wv.x*iv.x + wv.y*iv.y + wv.z*iv.z + wv.w*iv.w;
        }
    }
    const float4* w4 = (const float4*)(fc4_w + (size_t)t * 128);
    const float*  lo = l_out + (size_t)bt * 4 * 128;     // uniform
    for (int k4 = 0; k4 < 32; ++k4) {
        float4 wv = w4[k4];
        #pragma unroll
        for (int bb = 0; bb < 4; ++bb) {
            float4 iv = *(const float4*)(lo + bb * 128 + k4 * 4);
            acc[bb] += wv.x*iv.x + wv.y*iv.y + wv.z*iv.z + wv.w*iv.w;
        }
    }
    #pragma unroll
    for (int bb = 0; bb < 4; ++bb)
        g_t[((size_t)bt * 4 + bb) * 384 + t] = fmaxf(acc[bb], 0.0f);
}

extern "C" void kernel_launch(void* const* d_in, const int* in_sizes, int n_in,
                              void* d_out, int out_size, void* d_ws, size_t ws_size,
                              hipStream_t stream) {
    const float* x   = (const float*)d_in[0];
    const float* l   = (const float*)d_in[1];
    const float* c1w = (const float*)d_in[2];
    const float* c1b = (const float*)d_in[3];
    const float* c2w = (const float*)d_in[4];
    const float* c2b = (const float*)d_in[5];
    const float* f1w = (const float*)d_in[6];
    const float* f1b = (const float*)d_in[7];
    const float* f2w = (const float*)d_in[8];
    const float* f2b = (const float*)d_in[9];
    const float* f3w = (const float*)d_in[10];
    const float* f3b = (const float*)d_in[11];
    const float* f4w = (const float*)d_in[12];
    const float* f4b = (const float*)d_in[13];

    float* out       = (float*)d_out;
    float* phi_out_p = out + PHI_OUT_OFF;
    float* gt_p      = out + GT_OFF;
    float* bbox_p    = out + BBOX_OFF;

    float* ws      = (float*)d_ws;
    float* phi     = ws + WS_PHI;
    float* h1      = ws + WS_H1;
    float* h2      = ws + WS_H2;
    float* partial = ws + WS_PART;
    float* l_out   = ws + WS_LOUT;
    float* w_t     = ws + WS_WT;

    repack_w2_kernel<<<72, 256, 0, stream>>>(c2w, w_t);
    foveate_kernel<<<6144, 256, 0, stream>>>(x, l, phi, bbox_p);
    conv1_kernel<<<512, 128, 0, stream>>>(phi, c1w, c1b, h1);
    conv2_kernel<<<512, 192, 0, stream>>>(h1, w_t, c2b, h2);
    fc1_partial_kernel<<<dim3(64, 4), 256, 0, stream>>>(h2, f1w, partial);
    fc12_finish_kernel<<<512, 256, 0, stream>>>(partial, f1b, l, f2w, f2b,
                                                phi_out_p, l_out);
    gt_kernel<<<128, 384, 0, stream>>>(phi_out_p, l_out, f3w, f3b, f4w, f4b, gt_p);
}

// Round 4
// 288.921 us; speedup vs baseline: 1.2349x; 1.0281x over previous
//
#include <hip/hip_runtime.h>

// ---------------------------------------------------------------------------
// GlimpseNetwork forward, fp32. Round 4: foveate fully unrolled per pyramid
// level (the runtime-kh loop serialized 16 dependent global loads -> latency
// bound); repack merged into foveate; fc1-finish + gt merged into fc_tail.
//
// d_out layout (floats): phi_out[512*256] | g_t[512*384] | bboxes[512*12*4]
// ws layout (floats):
//   phi  [0,        1572864)  foveate -> conv1
//   h1   [1572864,  2375680)  conv1 -> conv2
//   h2   [0,         819200)  conv2 -> fc1 (over dead phi)
//   part [1572864,  2097152)  fc1 -> fc_tail (over dead h1)
//   w_t  [2375680,  2394112)  repack (in foveate) -> conv2; no overlap
// ---------------------------------------------------------------------------

#define PHI_OUT_OFF 0
#define GT_OFF      131072
#define BBOX_OFF    327680

#define WS_PHI   0
#define WS_H1    1572864
#define WS_H2    0
#define WS_PART  1572864
#define WS_WT    2375680

// ---- Kernel 1: foveation, unrolled per level; blocks 0..71 also repack ----
__global__ __launch_bounds__(256) void foveate_kernel(
    const float* __restrict__ x,     // [512,1,256,256]
    const float* __restrict__ l,     // [512,4,2]
    const float* __restrict__ c2w,   // [64,32,3,3]
    float* __restrict__ w_t,         // [288,64]
    float* __restrict__ phi,         // [512,12,16,16]
    float* __restrict__ bbox)        // [512,12,4]
{
    int blk = blockIdx.x;
    int t = threadIdx.x;

    // side job: repack conv2 weights [64,32,3,3] -> [c*9+ky*3+kx][64]
    int gidx = blk * 256 + t;
    if (gidx < 18432) {
        int oc = gidx / 288, rr = gidx % 288;
        w_t[rr * 64 + oc] = c2w[gidx];
    }

    int b  = blk / 12;
    int ji = blk % 12;
    int j  = ji / 3;
    int i  = ji % 3;
    int gh   = 16 << i;
    int half = gh >> 1;

    float l0 = l[(b * 4 + j) * 2 + 0];
    float l1 = l[(b * 4 + j) * 2 + 1];
    int sx = (int)(0.5f * ((l0 + 1.0f) * 255.0f) - (float)half);
    int sy = (int)(0.5f * ((l1 + 1.0f) * 255.0f) - (float)half);
    sx = min(max(sx, 0), 256 - gh);
    sy = min(max(sy, 0), 256 - gh);

    int r = t >> 4, c = t & 15;
    const float* xb = x + (size_t)b * 65536;
    float s;
    if (i == 0) {
        s = xb[(sx + r) * 256 + sy + c];
    } else if (i == 1) {
        const float* p = xb + (sx + 2 * r) * 256 + sy + 2 * c;
        float v00 = p[0], v01 = p[1], v10 = p[256], v11 = p[257];
        s = ((v00 + v01) + (v10 + v11)) * 0.25f;
    } else {
        const float* p = xb + (sx + 4 * r) * 256 + sy + 4 * c;
        float v[16];
        #pragma unroll
        for (int dy = 0; dy < 4; ++dy) {
            #pragma unroll
            for (int dx = 0; dx < 4; ++dx)
                v[dy * 4 + dx] = p[dy * 256 + dx];   // 16 independent loads
        }
        float s0 = (v[0]  + v[1])  + (v[2]  + v[3]);
        float s1 = (v[4]  + v[5])  + (v[6]  + v[7]);
        float s2 = (v[8]  + v[9])  + (v[10] + v[11]);
        float s3 = (v[12] + v[13]) + (v[14] + v[15]);
        s = ((s0 + s1) + (s2 + s3)) * 0.0625f;
    }
    phi[((size_t)b * 12 + ji) * 256 + t] = s;

    if (t == 0) {
        float* bb = bbox + ((size_t)b * 12 + ji) * 4;
        bb[0] = (float)sy;
        bb[1] = (float)sx;
        bb[2] = (float)(sy + gh);
        bb[3] = (float)(sx + gh);
    }
}

// ---- Kernel 2: conv1 12->32, k4 s2, +bias, ReLU ---------------------------
__global__ __launch_bounds__(128) void conv1_kernel(
    const float* __restrict__ phi,   // [512,12,16,16]
    const float* __restrict__ w,     // [32,12,4,4]
    const float* __restrict__ bias,  // [32]
    float* __restrict__ out)         // [512,32,7,7]
{
    __shared__ float in_s[12 * 16 * 20];
    int b = blockIdx.x, t = threadIdx.x;
    const float* pin = phi + (size_t)b * 3072;
    for (int k = t; k < 3072; k += 128) {
        int c = k >> 8, q = k & 255, row = q >> 4, col = q & 15;
        in_s[(c * 16 + row) * 20 + col] = pin[k];
    }
    __syncthreads();
    if (t >= 112) return;
    int py = t >> 4, oc2 = t & 15, oc = oc2 * 2;

    float a0[7] = {0.f,0.f,0.f,0.f,0.f,0.f,0.f};
    float a1[7] = {0.f,0.f,0.f,0.f,0.f,0.f,0.f};
    for (int c = 0; c < 12; ++c) {
        for (int ky = 0; ky < 4; ++ky) {
            const float* rp = in_s + (c * 16 + 2 * py + ky) * 20;
            float4 r0 = *(const float4*)(rp);
            float4 r1 = *(const float4*)(rp + 4);
            float4 r2 = *(const float4*)(rp + 8);
            float4 r3 = *(const float4*)(rp + 12);
            float row[16] = {r0.x,r0.y,r0.z,r0.w, r1.x,r1.y,r1.z,r1.w,
                             r2.x,r2.y,r2.z,r2.w, r3.x,r3.y,r3.z,r3.w};
            float4 wa = *(const float4*)(w + (( oc      * 12 + c) * 4 + ky) * 4);
            float4 wb = *(const float4*)(w + (((oc + 1) * 12 + c) * 4 + ky) * 4);
            #pragma unroll
            for (int px = 0; px < 7; ++px) {
                int s2 = 2 * px;
                a0[px] += row[s2]*wa.x + row[s2+1]*wa.y + row[s2+2]*wa.z + row[s2+3]*wa.w;
                a1[px] += row[s2]*wb.x + row[s2+1]*wb.y + row[s2+2]*wb.z + row[s2+3]*wb.w;
            }
        }
    }
    float b0 = bias[oc], b1 = bias[oc + 1];
    float* o = out + (size_t)b * 1568 + oc * 49 + py * 7;
    #pragma unroll
    for (int px = 0; px < 7; ++px) {
        o[px]      = fmaxf(a0[px] + b0, 0.0f);
        o[px + 49] = fmaxf(a1[px] + b1, 0.0f);
    }
}

// ---- Kernel 3: conv2 32->64, k3 s1, +bias, ReLU ---------------------------
__global__ __launch_bounds__(192) void conv2_kernel(
    const float* __restrict__ h1,    // [512,32,7,7]
    const float* __restrict__ w_t,   // [288,64]
    const float* __restrict__ bias,  // [64]
    float* __restrict__ out)         // [512,1600]
{
    __shared__ float in_s[32 * 7 * 8];
    int b = blockIdx.x, t = threadIdx.x;
    const float* pin = h1 + (size_t)b * 1568;
    for (int k = t; k < 1568; k += 192) {
        int c = k / 49, q = k % 49, row = q / 7, col = q % 7;
        in_s[c * 56 + row * 8 + col] = pin[k];
    }
    __syncthreads();
    if (t >= 160) return;
    int py = t >> 5, oc2 = t & 31, oc = oc2 * 2;

    float a0[5] = {0.f,0.f,0.f,0.f,0.f};
    float a1[5] = {0.f,0.f,0.f,0.f,0.f};
    for (int c = 0; c < 32; ++c) {
        #pragma unroll
        for (int ky = 0; ky < 3; ++ky) {
            const float* rp = in_s + c * 56 + (py + ky) * 8;
            float4 q0 = *(const float4*)(rp);
            float4 q1 = *(const float4*)(rp + 4);
            float row[8] = {q0.x,q0.y,q0.z,q0.w, q1.x,q1.y,q1.z,q1.w};
            #pragma unroll
            for (int kx = 0; kx < 3; ++kx) {
                float2 wv = *(const float2*)(w_t + (c * 9 + ky * 3 + kx) * 64 + oc);
                #pragma unroll
                for (int px = 0; px < 5; ++px) {
                    a0[px] += row[px + kx] * wv.x;
                    a1[px] += row[px + kx] * wv.y;
                }
            }
        }
    }
    float b0 = bias[oc], b1 = bias[oc + 1];
    float* o = out + (size_t)b * 1600 + oc * 25 + py * 5;
    #pragma unroll
    for (int px = 0; px < 5; ++px) {
        o[px]      = fmaxf(a0[px] + b0, 0.0f);
        o[px + 25] = fmaxf(a1[px] + b1, 0.0f);
    }
}

// ---- Kernel 4: fc1 partial GEMM; inputs wave-uniform ----------------------
__global__ __launch_bounds__(256) void fc1_partial_kernel(
    const float* __restrict__ h2,      // [512,1600]
    const float* __restrict__ w,       // [256,1600]
    float* __restrict__ partial)       // [4,512,256]
{
    int bt = blockIdx.x, kc = blockIdx.y, t = threadIdx.x;
    const float4* wp = (const float4*)(w + (size_t)t * 1600 + kc * 400);
    const float*  hb = h2 + (size_t)bt * 8 * 1600 + kc * 400;
    float acc[8] = {0.f,0.f,0.f,0.f,0.f,0.f,0.f,0.f};
    for (int k4 = 0; k4 < 100; ++k4) {
        float4 wv = wp[k4];
        #pragma unroll
        for (int bb = 0; bb < 8; ++bb) {
            float4 iv = *(const float4*)(hb + bb * 1600 + k4 * 4);
            acc[bb] += wv.x*iv.x + wv.y*iv.y + wv.z*iv.z + wv.w*iv.w;
        }
    }
    float* pp = partial + ((size_t)kc * 512 + bt * 8) * 256 + t;
    #pragma unroll
    for (int bb = 0; bb < 8; ++bb) pp[bb * 256] = acc[bb];
}

// ---- Kernel 5: fc_tail = fc1-reduce+ReLU -> phi_out; fc2; fc3/fc4 -> g_t --
// grid 128 blocks (4 b each), 384 threads
__global__ __launch_bounds__(384) void fc_tail_kernel(
    const float* __restrict__ partial,  // [4,512,256]
    const float* __restrict__ fc1_b,    // [256]
    const float* __restrict__ l,        // [512,8]
    const float* __restrict__ fc2_w,    // [128,8]
    const float* __restrict__ fc2_b,    // [128]
    const float* __restrict__ fc3_w,    // [384,256]
    const float* __restrict__ fc3_b,    // [384]
    const float* __restrict__ fc4_w,    // [384,128]
    const float* __restrict__ fc4_b,    // [384]
    float* __restrict__ phi_out,        // [512,256]
    float* __restrict__ g_t)            // [512,384]
{
    __shared__ float ph_s[4 * 256];
    __shared__ float lo_s[4 * 128];
    int bt = blockIdx.x, t = threadIdx.x;

    for (int idx = t; idx < 1024; idx += 384) {
        int bb = idx >> 8, ch = idx & 255;
        size_t gidx = ((size_t)(bt * 4 + bb)) * 256 + ch;
        float s = fc1_b[ch];
        #pragma unroll
        for (int kc = 0; kc < 4; ++kc) s += partial[(size_t)kc * 131072 + gidx];
        s = fmaxf(s, 0.0f);
        ph_s[idx] = s;
        phi_out[gidx] = s;
    }
    for (int idx = t; idx < 512; idx += 384) {
        int bb = idx >> 7, ch = idx & 127;
        int b = bt * 4 + bb;
        float a = fc2_b[ch];
        const float* lb = l + b * 8;
        const float* wr = fc2_w + ch * 8;
        #pragma unroll
        for (int m = 0; m < 8; ++m) a += lb[m] * wr[m];
        lo_s[idx] = fmaxf(a, 0.0f);
    }
    __syncthreads();

    float base = fc3_b[t] + fc4_b[t];
    float acc[4] = {base, base, base, base};
    const float4* w3 = (const float4*)(fc3_w + (size_t)t * 256);
    for (int k4 = 0; k4 < 64; ++k4) {
        float4 wv = w3[k4];
        #pragma unroll
        for (int bb = 0; bb < 4; ++bb) {
            float4 iv = *(const float4*)&ph_s[bb * 256 + k4 * 4];  // broadcast
            acc[bb] += wv.x*iv.x + wv.y*iv.y + wv.z*iv.z + wv.w*iv.w;
        }
    }
    const float4* w4 = (const float4*)(fc4_w + (size_t)t * 128);
    for (int k4 = 0; k4 < 32; ++k4) {
        float4 wv = w4[k4];
        #pragma unroll
        for (int bb = 0; bb < 4; ++bb) {
            float4 iv = *(const float4*)&lo_s[bb * 128 + k4 * 4];  // broadcast
            acc[bb] += wv.x*iv.x + wv.y*iv.y + wv.z*iv.z + wv.w*iv.w;
        }
    }
    #pragma unroll
    for (int bb = 0; bb < 4; ++bb)
        g_t[((size_t)bt * 4 + bb) * 384 + t] = fmaxf(acc[bb], 0.0f);
}

extern "C" void kernel_launch(void* const* d_in, const int* in_sizes, int n_in,
                              void* d_out, int out_size, void* d_ws, size_t ws_size,
                              hipStream_t stream) {
    const float* x   = (const float*)d_in[0];
    const float* l   = (const float*)d_in[1];
    const float* c1w = (const float*)d_in[2];
    const float* c1b = (const float*)d_in[3];
    const float* c2w = (const float*)d_in[4];
    const float* c2b = (const float*)d_in[5];
    const float* f1w = (const float*)d_in[6];
    const float* f1b = (const float*)d_in[7];
    const float* f2w = (const float*)d_in[8];
    const float* f2b = (const float*)d_in[9];
    const float* f3w = (const float*)d_in[10];
    const float* f3b = (const float*)d_in[11];
    const float* f4w = (const float*)d_in[12];
    const float* f4b = (const float*)d_in[13];

    float* out       = (float*)d_out;
    float* phi_out_p = out + PHI_OUT_OFF;
    float* gt_p      = out + GT_OFF;
    float* bbox_p    = out + BBOX_OFF;

    float* ws      = (float*)d_ws;
    float* phi     = ws + WS_PHI;
    float* h1      = ws + WS_H1;
    float* h2      = ws + WS_H2;
    float* partial = ws + WS_PART;
    float* w_t     = ws + WS_WT;

    foveate_kernel<<<6144, 256, 0, stream>>>(x, l, c2w, w_t, phi, bbox_p);
    conv1_kernel<<<512, 128, 0, stream>>>(phi, c1w, c1b, h1);
    conv2_kernel<<<512, 192, 0, stream>>>(h1, w_t, c2b, h2);
    fc1_partial_kernel<<<dim3(64, 4), 256, 0, stream>>>(h2, f1w, partial);
    fc_tail_kernel<<<128, 384, 0, stream>>>(partial, f1b, l, f2w, f2b,
                                            f3w, f3b, f4w, f4b,
                                            phi_out_p, gt_p);
}

// Round 5
// 271.952 us; speedup vs baseline: 1.3120x; 1.0624x over previous
//
#include <hip/hip_runtime.h>

// ---------------------------------------------------------------------------
// GlimpseNetwork forward, fp32. Round 5: conv1+conv2 fused per-image (h1 in
// LDS), 1 oc/thread decompositions for 2x waves/SIMD; fc1 split 8 ways
// (512 blocks); fc_tail 256 blocks. Discriminates kernel-time vs fixed
// harness overhead in dur_us.
//
// d_out layout (floats): phi_out[512*256] | g_t[512*384] | bboxes[512*12*4]
// ws layout (floats):
//   phi  [0,        1572864)   foveate -> conv_fused
//   h2   [1572864,  2392064)   conv_fused -> fc1
//   part [2392064,  3440640)   fc1 -> fc_tail   [8,512,256]
//   w_t  [3440640,  3459072)   repack (in foveate) -> conv_fused
// ---------------------------------------------------------------------------

#define PHI_OUT_OFF 0
#define GT_OFF      131072
#define BBOX_OFF    327680

#define WS_PHI   0
#define WS_H2    1572864
#define WS_PART  2392064
#define WS_WT    3440640

// ---- Kernel 1: foveation, unrolled per level; blocks 0..71 also repack ----
__global__ __launch_bounds__(256) void foveate_kernel(
    const float* __restrict__ x,     // [512,1,256,256]
    const float* __restrict__ l,     // [512,4,2]
    const float* __restrict__ c2w,   // [64,32,3,3]
    float* __restrict__ w_t,         // [288,64]
    float* __restrict__ phi,         // [512,12,16,16]
    float* __restrict__ bbox)        // [512,12,4]
{
    int blk = blockIdx.x;
    int t = threadIdx.x;

    int gidx = blk * 256 + t;
    if (gidx < 18432) {
        int oc = gidx / 288, rr = gidx % 288;
        w_t[rr * 64 + oc] = c2w[gidx];
    }

    int b  = blk / 12;
    int ji = blk % 12;
    int j  = ji / 3;
    int i  = ji % 3;
    int gh   = 16 << i;
    int half = gh >> 1;

    float l0 = l[(b * 4 + j) * 2 + 0];
    float l1 = l[(b * 4 + j) * 2 + 1];
    int sx = (int)(0.5f * ((l0 + 1.0f) * 255.0f) - (float)half);
    int sy = (int)(0.5f * ((l1 + 1.0f) * 255.0f) - (float)half);
    sx = min(max(sx, 0), 256 - gh);
    sy = min(max(sy, 0), 256 - gh);

    int r = t >> 4, c = t & 15;
    const float* xb = x + (size_t)b * 65536;
    float s;
    if (i == 0) {
        s = xb[(sx + r) * 256 + sy + c];
    } else if (i == 1) {
        const float* p = xb + (sx + 2 * r) * 256 + sy + 2 * c;
        float v00 = p[0], v01 = p[1], v10 = p[256], v11 = p[257];
        s = ((v00 + v01) + (v10 + v11)) * 0.25f;
    } else {
        const float* p = xb + (sx + 4 * r) * 256 + sy + 4 * c;
        float v[16];
        #pragma unroll
        for (int dy = 0; dy < 4; ++dy) {
            #pragma unroll
            for (int dx = 0; dx < 4; ++dx)
                v[dy * 4 + dx] = p[dy * 256 + dx];
        }
        float s0 = (v[0]  + v[1])  + (v[2]  + v[3]);
        float s1 = (v[4]  + v[5])  + (v[6]  + v[7]);
        float s2 = (v[8]  + v[9])  + (v[10] + v[11]);
        float s3 = (v[12] + v[13]) + (v[14] + v[15]);
        s = ((s0 + s1) + (s2 + s3)) * 0.0625f;
    }
    phi[((size_t)b * 12 + ji) * 256 + t] = s;

    if (t == 0) {
        float* bb = bbox + ((size_t)b * 12 + ji) * 4;
        bb[0] = (float)sy;
        bb[1] = (float)sx;
        bb[2] = (float)(sy + gh);
        bb[3] = (float)(sx + gh);
    }
}

// ---- Kernel 2: fused conv1 (12->32 k4s2) + conv2 (32->64 k3s1), per image -
// 512 blocks, 256 threads. h1 lives in LDS; only h2 goes to global.
__global__ __launch_bounds__(256) void conv_fused_kernel(
    const float* __restrict__ phi,   // [512,12,16,16]
    const float* __restrict__ c1w,   // [32,12,4,4]
    const float* __restrict__ c1b,   // [32]
    const float* __restrict__ w_t,   // [288,64] repacked conv2 weights
    const float* __restrict__ c2b,   // [64]
    float* __restrict__ h2)          // [512,1600]
{
    __shared__ float in_s[12 * 16 * 20];  // conv1 input, rows padded 16->20
    __shared__ float h1_s[32 * 7 * 8];    // conv1 output, rows padded 7->8
    int b = blockIdx.x, t = threadIdx.x;

    const float* pin = phi + (size_t)b * 3072;
    for (int k = t; k < 3072; k += 256) {
        int c = k >> 8, q = k & 255, row = q >> 4, col = q & 15;
        in_s[(c * 16 + row) * 20 + col] = pin[k];
    }
    __syncthreads();

    // conv1: t = py*32 + oc, 224 active; 1 oc x 7 px per thread
    if (t < 224) {
        int py = t >> 5, oc = t & 31;
        float a[7] = {0.f,0.f,0.f,0.f,0.f,0.f,0.f};
        for (int c = 0; c < 12; ++c) {
            #pragma unroll
            for (int ky = 0; ky < 4; ++ky) {
                const float* rp = in_s + (c * 16 + 2 * py + ky) * 20;
                float4 r0 = *(const float4*)(rp);
                float4 r1 = *(const float4*)(rp + 4);
                float4 r2 = *(const float4*)(rp + 8);
                float4 r3 = *(const float4*)(rp + 12);
                float row[16] = {r0.x,r0.y,r0.z,r0.w, r1.x,r1.y,r1.z,r1.w,
                                 r2.x,r2.y,r2.z,r2.w, r3.x,r3.y,r3.z,r3.w};
                float4 wv = *(const float4*)(c1w + ((oc * 12 + c) * 4 + ky) * 4);
                #pragma unroll
                for (int px = 0; px < 7; ++px) {
                    int s2 = 2 * px;
                    a[px] += row[s2]*wv.x + row[s2+1]*wv.y
                           + row[s2+2]*wv.z + row[s2+3]*wv.w;
                }
            }
        }
        float bv = c1b[oc];
        #pragma unroll
        for (int px = 0; px < 7; ++px)
            h1_s[oc * 56 + py * 8 + px] = fmaxf(a[px] + bv, 0.0f);
    }
    __syncthreads();

    // conv2: idx = py*64 + oc (320 items over 256 threads, 2 passes)
    for (int idx = t; idx < 320; idx += 256) {
        int py = idx >> 6, oc = idx & 63;
        float a[5] = {0.f,0.f,0.f,0.f,0.f};
        for (int c = 0; c < 32; ++c) {
            #pragma unroll
            for (int ky = 0; ky < 3; ++ky) {
                const float* rp = h1_s + c * 56 + (py + ky) * 8;  // broadcast
                float4 q0 = *(const float4*)(rp);
                float4 q1 = *(const float4*)(rp + 4);
                float row[8] = {q0.x,q0.y,q0.z,q0.w, q1.x,q1.y,q1.z,q1.w};
                #pragma unroll
                for (int kx = 0; kx < 3; ++kx) {
                    float wv = w_t[(c * 9 + ky * 3 + kx) * 64 + oc];  // coalesced
                    #pragma unroll
                    for (int px = 0; px < 5; ++px)
                        a[px] += row[px + kx] * wv;
                }
            }
        }
        float bv = c2b[oc];
        float* o = h2 + (size_t)b * 1600 + oc * 25 + py * 5;
        #pragma unroll
        for (int px = 0; px < 5; ++px)
            o[px] = fmaxf(a[px] + bv, 0.0f);
    }
}

// ---- Kernel 3: fc1 partial GEMM, 8 k-chunks of 200 ------------------------
// grid (64 batch-tiles of 8, 8 k-chunks), 256 threads = out channels
__global__ __launch_bounds__(256) void fc1_partial_kernel(
    const float* __restrict__ h2,      // [512,1600]
    const float* __restrict__ w,       // [256,1600]
    float* __restrict__ partial)       // [8,512,256]
{
    int bt = blockIdx.x, kc = blockIdx.y, t = threadIdx.x;
    const float4* wp = (const float4*)(w + (size_t)t * 1600 + kc * 200);
    const float*  hb = h2 + (size_t)bt * 8 * 1600 + kc * 200;
    float acc[8] = {0.f,0.f,0.f,0.f,0.f,0.f,0.f,0.f};
    for (int k4 = 0; k4 < 50; ++k4) {
        float4 wv = wp[k4];
        #pragma unroll
        for (int bb = 0; bb < 8; ++bb) {
            float4 iv = *(const float4*)(hb + bb * 1600 + k4 * 4);
            acc[bb] += wv.x*iv.x + wv.y*iv.y + wv.z*iv.z + wv.w*iv.w;
        }
    }
    float* pp = partial + ((size_t)kc * 512 + bt * 8) * 256 + t;
    #pragma unroll
    for (int bb = 0; bb < 8; ++bb) pp[bb * 256] = acc[bb];
}

// ---- Kernel 4: fc_tail = fc1-reduce+ReLU -> phi_out; fc2; fc3/fc4 -> g_t --
// grid 256 blocks (2 images each), 384 threads
__global__ __launch_bounds__(384) void fc_tail_kernel(
    const float* __restrict__ partial,  // [8,512,256]
    const float* __restrict__ fc1_b,    // [256]
    const float* __restrict__ l,        // [512,8]
    const float* __restrict__ fc2_w,    // [128,8]
    const float* __restrict__ fc2_b,    // [128]
    const float* __restrict__ fc3_w,    // [384,256]
    const float* __restrict__ fc3_b,    // [384]
    const float* __restrict__ fc4_w,    // [384,128]
    const float* __restrict__ fc4_b,    // [384]
    float* __restrict__ phi_out,        // [512,256]
    float* __restrict__ g_t)            // [512,384]
{
    __shared__ float ph_s[2 * 256];
    __shared__ float lo_s[2 * 128];
    int bt = blockIdx.x, t = threadIdx.x;

    for (int idx = t; idx < 512; idx += 384) {
        int bb = idx >> 8, ch = idx & 255;
        size_t gidx = ((size_t)(bt * 2 + bb)) * 256 + ch;
        float s = fc1_b[ch];
        #pragma unroll
        for (int kc = 0; kc < 8; ++kc) s += partial[(size_t)kc * 131072 + gidx];
        s = fmaxf(s, 0.0f);
        ph_s[idx] = s;
        phi_out[gidx] = s;
    }
    for (int idx = t; idx < 256; idx += 384) {
        int bb = idx >> 7, ch = idx & 127;
        int b = bt * 2 + bb;
        float a = fc2_b[ch];
        const float* lb = l + b * 8;
        const float* wr = fc2_w + ch * 8;
        #pragma unroll
        for (int m = 0; m < 8; ++m) a += lb[m] * wr[m];
        lo_s[idx] = fmaxf(a, 0.0f);
    }
    __syncthreads();

    float base = fc3_b[t] + fc4_b[t];
    float acc[2] = {base, base};
    const float4* w3 = (const float4*)(fc3_w + (size_t)t * 256);
    for (int k4 = 0; k4 < 64; ++k4) {
        float4 wv = w3[k4];
        #pragma unroll
        for (int bb = 0; bb < 2; ++bb) {
            float4 iv = *(const float4*)&ph_s[bb * 256 + k4 * 4];
            acc[bb] += wv.x*iv.x + wv.y*iv.y + wv.z*iv.z + wv.w*iv.w;
        }
    }
    const float4* w4 = (const float4*)(fc4_w + (size_t)t * 128);
    for (int k4 = 0; k4 < 32; ++k4) {
        float4 wv = w4[k4];
        #pragma unroll
        for (int bb = 0; bb < 2; ++bb) {
            float4 iv = *(const float4*)&lo_s[bb * 128 + k4 * 4];
            acc[bb] += wv.x*iv.x + wv.y*iv.y + wv.z*iv.z + wv.w*iv.w;
        }
    }
    #pragma unroll
    for (int bb = 0; bb < 2; ++bb)
        g_t[((size_t)bt * 2 + bb) * 384 + t] = fmaxf(acc[bb], 0.0f);
}

extern "C" void kernel_launch(void* const* d_in, const int* in_sizes, int n_in,
                              void* d_out, int out_size, void* d_ws, size_t ws_size,
                              hipStream_t stream) {
    const float* x   = (const float*)d_in[0];
    const float* l   = (const float*)d_in[1];
    const float* c1w = (const float*)d_in[2];
    const float* c1b = (const float*)d_in[3];
    const float* c2w = (const float*)d_in[4];
    const float* c2b = (const float*)d_in[5];
    const float* f1w = (const float*)d_in[6];
    const float* f1b = (const float*)d_in[7];
    const float* f2w = (const float*)d_in[8];
    const float* f2b = (const float*)d_in[9];
    const float* f3w = (const float*)d_in[10];
    const float* f3b = (const float*)d_in[11];
    const float* f4w = (const float*)d_in[12];
    const float* f4b = (const float*)d_in[13];

    float* out       = (float*)d_out;
    float* phi_out_p = out + PHI_OUT_OFF;
    float* gt_p      = out + GT_OFF;
    float* bbox_p    = out + BBOX_OFF;

    float* ws      = (float*)d_ws;
    float* phi     = ws + WS_PHI;
    float* h2      = ws + WS_H2;
    float* partial = ws + WS_PART;
    float* w_t     = ws + WS_WT;

    foveate_kernel<<<6144, 256, 0, stream>>>(x, l, c2w, w_t, phi, bbox_p);
    conv_fused_kernel<<<512, 256, 0, stream>>>(phi, c1w, c1b, w_t, c2b, h2);
    fc1_partial_kernel<<<dim3(64, 8), 256, 0, stream>>>(h2, f1w, partial);
    fc_tail_kernel<<<256, 384, 0, stream>>>(partial, f1b, l, f2w, f2b,
                                            f3w, f3b, f4w, f4b,
                                            phi_out_p, gt_p);
}

// Round 6
// 267.952 us; speedup vs baseline: 1.3315x; 1.0149x over previous
//
#include <hip/hip_runtime.h>

// ---------------------------------------------------------------------------
// GlimpseNetwork forward, fp32. Round 6: foveate fused INTO the conv kernel
// (per-image locality: pooled pixels land directly in LDS in_s; no phi global
// round-trip, one fewer launch). Pipeline:
//   repack (72 blk)  : conv2 weights -> [c*9+ky*3+kx][64]
//   glimpse_conv(512): foveate->in_s, conv1->h1_s(LDS), conv2->h2, bbox out
//   fc1_partial(64x8): K-split GEMM -> partial
//   fc_tail (256)    : reduce+ReLU->phi_out, fc2, fc3/fc4 -> g_t
//
// d_out layout (floats): phi_out[512*256] | g_t[512*384] | bboxes[512*12*4]
// ws layout (floats):
//   h2   [0,        819200)    glimpse_conv -> fc1
//   part [819200,  1867776)    fc1 -> fc_tail   [8,512,256]
//   w_t  [1867776, 1886208)    repack -> glimpse_conv
// ---------------------------------------------------------------------------

#define PHI_OUT_OFF 0
#define GT_OFF      131072
#define BBOX_OFF    327680

#define WS_H2    0
#define WS_PART  819200
#define WS_WT    1867776

// ---- Kernel 0: repack conv2 weights [64,32,3,3] -> [c*9+ky*3+kx][64] ------
__global__ __launch_bounds__(256) void repack_w2_kernel(
    const float* __restrict__ w, float* __restrict__ w_t)
{
    int idx = blockIdx.x * 256 + threadIdx.x;
    if (idx < 18432) {
        int oc = idx / 288, r = idx % 288;
        w_t[r * 64 + oc] = w[idx];
    }
}

// ---- Kernel 1: fused foveate + conv1 + conv2, one block per image ---------
// 512 blocks, 256 threads. LDS: in_s 15.4 KB + h1_s 7.2 KB.
__global__ __launch_bounds__(256) void glimpse_conv_kernel(
    const float* __restrict__ x,     // [512,1,256,256]
    const float* __restrict__ l,     // [512,4,2]
    const float* __restrict__ c1w,   // [32,12,4,4]
    const float* __restrict__ c1b,   // [32]
    const float* __restrict__ w_t,   // [288,64]
    const float* __restrict__ c2b,   // [64]
    float* __restrict__ h2,          // [512,1600]
    float* __restrict__ bbox)        // [512,12,4]
{
    __shared__ float in_s[12 * 16 * 20];  // foveated pyramid, rows padded ->20
    __shared__ float h1_s[32 * 7 * 8];    // conv1 output, rows padded ->8
    int b = blockIdx.x, t = threadIdx.x;
    int r = t >> 4, c = t & 15;
    const float* xb = x + (size_t)b * 65536;

    // ---- foveate: 4 glimpses x 3 pyramid levels, direct to LDS ----
    #pragma unroll
    for (int j = 0; j < 4; ++j) {
        float l0 = l[(b * 4 + j) * 2 + 0];
        float l1 = l[(b * 4 + j) * 2 + 1];
        // level 0 (16x16, no pooling)
        {
            int sx = (int)(0.5f * ((l0 + 1.0f) * 255.0f) - 8.0f);
            int sy = (int)(0.5f * ((l1 + 1.0f) * 255.0f) - 8.0f);
            sx = min(max(sx, 0), 240);
            sy = min(max(sy, 0), 240);
            in_s[((j * 3 + 0) * 16 + r) * 20 + c] = xb[(sx + r) * 256 + sy + c];
        }
        // level 1 (32x32 -> 2x2 mean)
        {
            int sx = (int)(0.5f * ((l0 + 1.0f) * 255.0f) - 16.0f);
            int sy = (int)(0.5f * ((l1 + 1.0f) * 255.0f) - 16.0f);
            sx = min(max(sx, 0), 224);
            sy = min(max(sy, 0), 224);
            const float* p = xb + (sx + 2 * r) * 256 + sy + 2 * c;
            float v00 = p[0], v01 = p[1], v10 = p[256], v11 = p[257];
            in_s[((j * 3 + 1) * 16 + r) * 20 + c] =
                ((v00 + v01) + (v10 + v11)) * 0.25f;
        }
        // level 2 (64x64 -> 4x4 mean)
        {
            int sx = (int)(0.5f * ((l0 + 1.0f) * 255.0f) - 32.0f);
            int sy = (int)(0.5f * ((l1 + 1.0f) * 255.0f) - 32.0f);
            sx = min(max(sx, 0), 192);
            sy = min(max(sy, 0), 192);
            const float* p = xb + (sx + 4 * r) * 256 + sy + 4 * c;
            float v[16];
            #pragma unroll
            for (int dy = 0; dy < 4; ++dy)
                #pragma unroll
                for (int dx = 0; dx < 4; ++dx)
                    v[dy * 4 + dx] = p[dy * 256 + dx];  // independent loads
            float s0 = (v[0]  + v[1])  + (v[2]  + v[3]);
            float s1 = (v[4]  + v[5])  + (v[6]  + v[7]);
            float s2 = (v[8]  + v[9])  + (v[10] + v[11]);
            float s3 = (v[12] + v[13]) + (v[14] + v[15]);
            in_s[((j * 3 + 2) * 16 + r) * 20 + c] =
                ((s0 + s1) + (s2 + s3)) * 0.0625f;
        }
    }
    // bbox: threads 0..11, one per (j,i)
    if (t < 12) {
        int j = t / 3, i = t % 3;
        int gh = 16 << i, half = gh >> 1;
        float l0 = l[(b * 4 + j) * 2 + 0];
        float l1 = l[(b * 4 + j) * 2 + 1];
        int sx = (int)(0.5f * ((l0 + 1.0f) * 255.0f) - (float)half);
        int sy = (int)(0.5f * ((l1 + 1.0f) * 255.0f) - (float)half);
        sx = min(max(sx, 0), 256 - gh);
        sy = min(max(sy, 0), 256 - gh);
        float4 bbv = make_float4((float)sy, (float)sx,
                                 (float)(sy + gh), (float)(sx + gh));
        *(float4*)(bbox + ((size_t)b * 12 + t) * 4) = bbv;
    }
    __syncthreads();

    // ---- conv1: t = py*32 + oc, 224 active; 1 oc x 7 px ----
    if (t < 224) {
        int py = t >> 5, oc = t & 31;
        float a[7] = {0.f,0.f,0.f,0.f,0.f,0.f,0.f};
        for (int ch = 0; ch < 12; ++ch) {
            #pragma unroll
            for (int ky = 0; ky < 4; ++ky) {
                const float* rp = in_s + (ch * 16 + 2 * py + ky) * 20;
                float4 r0 = *(const float4*)(rp);
                float4 r1 = *(const float4*)(rp + 4);
                float4 r2 = *(const float4*)(rp + 8);
                float4 r3 = *(const float4*)(rp + 12);
                float row[16] = {r0.x,r0.y,r0.z,r0.w, r1.x,r1.y,r1.z,r1.w,
                                 r2.x,r2.y,r2.z,r2.w, r3.x,r3.y,r3.z,r3.w};
                float4 wv = *(const float4*)(c1w + ((oc * 12 + ch) * 4 + ky) * 4);
                #pragma unroll
                for (int px = 0; px < 7; ++px) {
                    int s2 = 2 * px;
                    a[px] += row[s2]*wv.x + row[s2+1]*wv.y
                           + row[s2+2]*wv.z + row[s2+3]*wv.w;
                }
            }
        }
        float bv = c1b[oc];
        #pragma unroll
        for (int px = 0; px < 7; ++px)
            h1_s[oc * 56 + py * 8 + px] = fmaxf(a[px] + bv, 0.0f);
    }
    __syncthreads();

    // ---- conv2: idx = py*64 + oc (320 items, 2 passes) ----
    for (int idx = t; idx < 320; idx += 256) {
        int py = idx >> 6, oc = idx & 63;
        float a[5] = {0.f,0.f,0.f,0.f,0.f};
        for (int ch = 0; ch < 32; ++ch) {
            #pragma unroll
            for (int ky = 0; ky < 3; ++ky) {
                const float* rp = h1_s + ch * 56 + (py + ky) * 8;  // broadcast
                float4 q0 = *(const float4*)(rp);
                float4 q1 = *(const float4*)(rp + 4);
                float row[8] = {q0.x,q0.y,q0.z,q0.w, q1.x,q1.y,q1.z,q1.w};
                #pragma unroll
                for (int kx = 0; kx < 3; ++kx) {
                    float wv = w_t[(ch * 9 + ky * 3 + kx) * 64 + oc];  // coalesced
                    #pragma unroll
                    for (int px = 0; px < 5; ++px)
                        a[px] += row[px + kx] * wv;
                }
            }
        }
        float bv = c2b[oc];
        float* o = h2 + (size_t)b * 1600 + oc * 25 + py * 5;
        #pragma unroll
        for (int px = 0; px < 5; ++px)
            o[px] = fmaxf(a[px] + bv, 0.0f);
    }
}

// ---- Kernel 2: fc1 partial GEMM, 8 k-chunks of 200 ------------------------
__global__ __launch_bounds__(256) void fc1_partial_kernel(
    const float* __restrict__ h2,      // [512,1600]
    const float* __restrict__ w,       // [256,1600]
    float* __restrict__ partial)       // [8,512,256]
{
    int bt = blockIdx.x, kc = blockIdx.y, t = threadIdx.x;
    const float4* wp = (const float4*)(w + (size_t)t * 1600 + kc * 200);
    const float*  hb = h2 + (size_t)bt * 8 * 1600 + kc * 200;
    float acc[8] = {0.f,0.f,0.f,0.f,0.f,0.f,0.f,0.f};
    for (int k4 = 0; k4 < 50; ++k4) {
        float4 wv = wp[k4];
        #pragma unroll
        for (int bb = 0; bb < 8; ++bb) {
            float4 iv = *(const float4*)(hb + bb * 1600 + k4 * 4);
            acc[bb] += wv.x*iv.x + wv.y*iv.y + wv.z*iv.z + wv.w*iv.w;
        }
    }
    float* pp = partial + ((size_t)kc * 512 + bt * 8) * 256 + t;
    #pragma unroll
    for (int bb = 0; bb < 8; ++bb) pp[bb * 256] = acc[bb];
}

// ---- Kernel 3: fc_tail = fc1-reduce+ReLU -> phi_out; fc2; fc3/fc4 -> g_t --
__global__ __launch_bounds__(384) void fc_tail_kernel(
    const float* __restrict__ partial,  // [8,512,256]
    const float* __restrict__ fc1_b,    // [256]
    const float* __restrict__ l,        // [512,8]
    const float* __restrict__ fc2_w,    // [128,8]
    const float* __restrict__ fc2_b,    // [128]
    const float* __restrict__ fc3_w,    // [384,256]
    const float* __restrict__ fc3_b,    // [384]
    const float* __restrict__ fc4_w,    // [384,128]
    const float* __restrict__ fc4_b,    // [384]
    float* __restrict__ phi_out,        // [512,256]
    float* __restrict__ g_t)            // [512,384]
{
    __shared__ float ph_s[2 * 256];
    __shared__ float lo_s[2 * 128];
    int bt = blockIdx.x, t = threadIdx.x;

    for (int idx = t; idx < 512; idx += 384) {
        int bb = idx >> 8, ch = idx & 255;
        size_t gidx = ((size_t)(bt * 2 + bb)) * 256 + ch;
        float s = fc1_b[ch];
        #pragma unroll
        for (int kc = 0; kc < 8; ++kc) s += partial[(size_t)kc * 131072 + gidx];
        s = fmaxf(s, 0.0f);
        ph_s[idx] = s;
        phi_out[gidx] = s;
    }
    for (int idx = t; idx < 256; idx += 384) {
        int bb = idx >> 7, ch = idx & 127;
        int b = bt * 2 + bb;
        float a = fc2_b[ch];
        const float* lb = l + b * 8;
        const float* wr = fc2_w + ch * 8;
        #pragma unroll
        for (int m = 0; m < 8; ++m) a += lb[m] * wr[m];
        lo_s[idx] = fmaxf(a, 0.0f);
    }
    __syncthreads();

    float base = fc3_b[t] + fc4_b[t];
    float acc[2] = {base, base};
    const float4* w3 = (const float4*)(fc3_w + (size_t)t * 256);
    for (int k4 = 0; k4 < 64; ++k4) {
        float4 wv = w3[k4];
        #pragma unroll
        for (int bb = 0; bb < 2; ++bb) {
            float4 iv = *(const float4*)&ph_s[bb * 256 + k4 * 4];
            acc[bb] += wv.x*iv.x + wv.y*iv.y + wv.z*iv.z + wv.w*iv.w;
        }
    }
    const float4* w4 = (const float4*)(fc4_w + (size_t)t * 128);
    for (int k4 = 0; k4 < 32; ++k4) {
        float4 wv = w4[k4];
        #pragma unroll
        for (int bb = 0; bb < 2; ++bb) {
            float4 iv = *(const float4*)&lo_s[bb * 128 + k4 * 4];
            acc[bb] += wv.x*iv.x + wv.y*iv.y + wv.z*iv.z + wv.w*iv.w;
        }
    }
    #pragma unroll
    for (int bb = 0; bb < 2; ++bb)
        g_t[((size_t)bt * 2 + bb) * 384 + t] = fmaxf(acc[bb], 0.0f);
}

extern "C" void kernel_launch(void* const* d_in, const int* in_sizes, int n_in,
                              void* d_out, int out_size, void* d_ws, size_t ws_size,
                              hipStream_t stream) {
    const float* x   = (const float*)d_in[0];
    const float* l   = (const float*)d_in[1];
    const float* c1w = (const float*)d_in[2];
    const float* c1b = (const float*)d_in[3];
    const float* c2w = (const float*)d_in[4];
    const float* c2b = (const float*)d_in[5];
    const float* f1w = (const float*)d_in[6];
    const float* f1b = (const float*)d_in[7];
    const float* f2w = (const float*)d_in[8];
    const float* f2b = (const float*)d_in[9];
    const float* f3w = (const float*)d_in[10];
    const float* f3b = (const float*)d_in[11];
    const float* f4w = (const float*)d_in[12];
    const float* f4b = (const float*)d_in[13];

    float* out       = (float*)d_out;
    float* phi_out_p = out + PHI_OUT_OFF;
    float* gt_p      = out + GT_OFF;
    float* bbox_p    = out + BBOX_OFF;

    float* ws      = (float*)d_ws;
    float* h2      = ws + WS_H2;
    float* partial = ws + WS_PART;
    float* w_t     = ws + WS_WT;

    repack_w2_kernel<<<72, 256, 0, stream>>>(c2w, w_t);
    glimpse_conv_kernel<<<512, 256, 0, stream>>>(x, l, c1w, c1b, w_t, c2b,
                                                 h2, bbox_p);
    fc1_partial_kernel<<<dim3(64, 8), 256, 0, stream>>>(h2, f1w, partial);
    fc_tail_kernel<<<256, 384, 0, stream>>>(partial, f1b, l, f2w, f2b,
                                            f3w, f3b, f4w, f4b,
                                            phi_out_p, gt_p);
}

// Round 8
// 267.122 us; speedup vs baseline: 1.3357x; 1.0031x over previous
//
#include <hip/hip_runtime.h>

// ---------------------------------------------------------------------------
// GlimpseNetwork forward, fp32. Round 8: revert to the 4-launch round-6
// structure (cooperative launch silently fails under graph capture) +
// conv1-weight repack (w1t) so conv1 weight reads are lane-coalesced.
// Pipeline:
//   repack (96 blk)  : c2w -> w2t[r][64oc];  c1w -> w1t[(ch*4+ky)][kx][32oc]
//   glimpse_conv(512): foveate->in_s(LDS), conv1->h1_s(LDS), conv2->h2, bbox
//   fc1_partial(64x8): K-split GEMM -> partial
//   fc_tail (256)    : reduce+ReLU->phi_out, fc2, fc3/fc4 -> g_t
//
// d_out layout (floats): phi_out[512*256] | g_t[512*384] | bboxes[512*12*4]
// ws (floats): h2[0,819200) part[819200,1867776) w2t[1867776,1886208)
//              w1t[1886208,1892352)
// ---------------------------------------------------------------------------

#define PHI_OUT_OFF 0
#define GT_OFF      131072
#define BBOX_OFF    327680

#define WS_H2    0
#define WS_PART  819200
#define WS_W2T   1867776
#define WS_W1T   1886208

// ---- Kernel 0: weight repacks --------------------------------------------
__global__ __launch_bounds__(256) void repack_kernel(
    const float* __restrict__ c2w,   // [64,32,3,3]
    const float* __restrict__ c1w,   // [32,12,4,4]
    float* __restrict__ w2t,         // [288,64]
    float* __restrict__ w1t)         // [48,4,32]
{
    int idx = blockIdx.x * 256 + threadIdx.x;
    if (idx < 18432) {                         // conv2: [oc][r] -> [r][64oc]
        int oc = idx / 288, r = idx % 288;
        w2t[r * 64 + oc] = c2w[idx];
    }
    int g1 = idx - 18432;
    if (g1 >= 0 && g1 < 6144) {                // conv1 -> [(ch*4+ky)][kx][32oc]
        int oc = g1 / 192, rem = g1 % 192;
        int ch = rem / 16, kk = rem % 16, ky = kk / 4, kx = kk % 4;
        w1t[(ch * 4 + ky) * 128 + kx * 32 + oc] = c1w[g1];
    }
}

// ---- Kernel 1: fused foveate + conv1 + conv2, one block per image ---------
// 512 blocks, 256 threads. LDS: in_s 15.4 KB + h1_s 7.2 KB.
__global__ __launch_bounds__(256) void glimpse_conv_kernel(
    const float* __restrict__ x,     // [512,1,256,256]
    const float* __restrict__ l,     // [512,4,2]
    const float* __restrict__ w1t,   // [48,4,32]
    const float* __restrict__ c1b,   // [32]
    const float* __restrict__ w2t,   // [288,64]
    const float* __restrict__ c2b,   // [64]
    float* __restrict__ h2,          // [512,1600]
    float* __restrict__ bbox)        // [512,12,4]
{
    __shared__ float in_s[12 * 16 * 20];  // foveated pyramid, rows padded ->20
    __shared__ float h1_s[32 * 7 * 8];    // conv1 output, rows padded ->8
    int b = blockIdx.x, t = threadIdx.x;
    int r = t >> 4, c = t & 15;
    const float* xb = x + (size_t)b * 65536;

    // ---- foveate: 4 glimpses x 3 pyramid levels, direct to LDS ----
    #pragma unroll
    for (int j = 0; j < 4; ++j) {
        float l0 = l[(b * 4 + j) * 2 + 0];
        float l1 = l[(b * 4 + j) * 2 + 1];
        {   // level 0 (16x16)
            int sx = (int)(0.5f * ((l0 + 1.0f) * 255.0f) - 8.0f);
            int sy = (int)(0.5f * ((l1 + 1.0f) * 255.0f) - 8.0f);
            sx = min(max(sx, 0), 240);
            sy = min(max(sy, 0), 240);
            in_s[((j * 3 + 0) * 16 + r) * 20 + c] = xb[(sx + r) * 256 + sy + c];
        }
        {   // level 1 (32x32 -> 2x2 mean)
            int sx = (int)(0.5f * ((l0 + 1.0f) * 255.0f) - 16.0f);
            int sy = (int)(0.5f * ((l1 + 1.0f) * 255.0f) - 16.0f);
            sx = min(max(sx, 0), 224);
            sy = min(max(sy, 0), 224);
            const float* p = xb + (sx + 2 * r) * 256 + sy + 2 * c;
            float v00 = p[0], v01 = p[1], v10 = p[256], v11 = p[257];
            in_s[((j * 3 + 1) * 16 + r) * 20 + c] =
                ((v00 + v01) + (v10 + v11)) * 0.25f;
        }
        {   // level 2 (64x64 -> 4x4 mean)
            int sx = (int)(0.5f * ((l0 + 1.0f) * 255.0f) - 32.0f);
            int sy = (int)(0.5f * ((l1 + 1.0f) * 255.0f) - 32.0f);
            sx = min(max(sx, 0), 192);
            sy = min(max(sy, 0), 192);
            const float* p = xb + (sx + 4 * r) * 256 + sy + 4 * c;
            float v[16];
            #pragma unroll
            for (int dy = 0; dy < 4; ++dy)
                #pragma unroll
                for (int dx = 0; dx < 4; ++dx)
                    v[dy * 4 + dx] = p[dy * 256 + dx];
            float s0 = (v[0]  + v[1])  + (v[2]  + v[3]);
            float s1 = (v[4]  + v[5])  + (v[6]  + v[7]);
            float s2 = (v[8]  + v[9])  + (v[10] + v[11]);
            float s3 = (v[12] + v[13]) + (v[14] + v[15]);
            in_s[((j * 3 + 2) * 16 + r) * 20 + c] =
                ((s0 + s1) + (s2 + s3)) * 0.0625f;
        }
    }
    if (t < 12) {
        int j = t / 3, i = t % 3;
        int gh = 16 << i, half = gh >> 1;
        float l0 = l[(b * 4 + j) * 2 + 0];
        float l1 = l[(b * 4 + j) * 2 + 1];
        int sx = (int)(0.5f * ((l0 + 1.0f) * 255.0f) - (float)half);
        int sy = (int)(0.5f * ((l1 + 1.0f) * 255.0f) - (float)half);
        sx = min(max(sx, 0), 256 - gh);
        sy = min(max(sy, 0), 256 - gh);
        float4 bbv = make_float4((float)sy, (float)sx,
                                 (float)(sy + gh), (float)(sx + gh));
        *(float4*)(bbox + ((size_t)b * 12 + t) * 4) = bbv;
    }
    __syncthreads();

    // ---- conv1: t = py*32 + oc, 224 active; coalesced w1t reads ----
    if (t < 224) {
        int py = t >> 5, oc = t & 31;
        float a[7] = {0.f,0.f,0.f,0.f,0.f,0.f,0.f};
        for (int ch = 0; ch < 12; ++ch) {
            #pragma unroll
            for (int ky = 0; ky < 4; ++ky) {
                const float* rp = in_s + (ch * 16 + 2 * py + ky) * 20;
                float4 r0 = *(const float4*)(rp);
                float4 r1 = *(const float4*)(rp + 4);
                float4 r2 = *(const float4*)(rp + 8);
                float4 r3 = *(const float4*)(rp + 12);
                float row[16] = {r0.x,r0.y,r0.z,r0.w, r1.x,r1.y,r1.z,r1.w,
                                 r2.x,r2.y,r2.z,r2.w, r3.x,r3.y,r3.z,r3.w};
                const float* wp = w1t + (ch * 4 + ky) * 128 + oc;  // lane-coalesced
                float w0 = wp[0], w1 = wp[32], w2 = wp[64], w3 = wp[96];
                #pragma unroll
                for (int px = 0; px < 7; ++px) {
                    int s2 = 2 * px;
                    a[px] += row[s2]*w0 + row[s2+1]*w1
                           + row[s2+2]*w2 + row[s2+3]*w3;
                }
            }
        }
        float bv = c1b[oc];
        #pragma unroll
        for (int px = 0; px < 7; ++px)
            h1_s[oc * 56 + py * 8 + px] = fmaxf(a[px] + bv, 0.0f);
    }
    __syncthreads();

    // ---- conv2: idx = py*64 + oc (320 items, 2 passes) ----
    for (int idx = t; idx < 320; idx += 256) {
        int py = idx >> 6, oc = idx & 63;
        float a[5] = {0.f,0.f,0.f,0.f,0.f};
        for (int ch = 0; ch < 32; ++ch) {
            #pragma unroll
            for (int ky = 0; ky < 3; ++ky) {
                const float* rp = h1_s + ch * 56 + (py + ky) * 8;  // broadcast
                float4 q0 = *(const float4*)(rp);
                float4 q1 = *(const float4*)(rp + 4);
                float row[8] = {q0.x,q0.y,q0.z,q0.w, q1.x,q1.y,q1.z,q1.w};
                #pragma unroll
                for (int kx = 0; kx < 3; ++kx) {
                    float wv = w2t[(ch * 9 + ky * 3 + kx) * 64 + oc];  // coalesced
                    #pragma unroll
                    for (int px = 0; px < 5; ++px)
                        a[px] += row[px + kx] * wv;
                }
            }
        }
        float bv = c2b[oc];
        float* o = h2 + (size_t)b * 1600 + oc * 25 + py * 5;
        #pragma unroll
        for (int px = 0; px < 5; ++px)
            o[px] = fmaxf(a[px] + bv, 0.0f);
    }
}

// ---- Kernel 2: fc1 partial GEMM, 8 k-chunks of 200 ------------------------
__global__ __launch_bounds__(256) void fc1_partial_kernel(
    const float* __restrict__ h2,      // [512,1600]
    const float* __restrict__ w,       // [256,1600]
    float* __restrict__ partial)       // [8,512,256]
{
    int bt = blockIdx.x, kc = blockIdx.y, t = threadIdx.x;
    const float4* wp = (const float4*)(w + (size_t)t * 1600 + kc * 200);
    const float*  hb = h2 + (size_t)bt * 8 * 1600 + kc * 200;
    float acc[8] = {0.f,0.f,0.f,0.f,0.f,0.f,0.f,0.f};
    for (int k4 = 0; k4 < 50; ++k4) {
        float4 wv = wp[k4];
        #pragma unroll
        for (int bb = 0; bb < 8; ++bb) {
            float4 iv = *(const float4*)(hb + bb * 1600 + k4 * 4);
            acc[bb] += wv.x*iv.x + wv.y*iv.y + wv.z*iv.z + wv.w*iv.w;
        }
    }
    float* pp = partial + ((size_t)kc * 512 + bt * 8) * 256 + t;
    #pragma unroll
    for (int bb = 0; bb < 8; ++bb) pp[bb * 256] = acc[bb];
}

// ---- Kernel 3: fc_tail = fc1-reduce+ReLU -> phi_out; fc2; fc3/fc4 -> g_t --
__global__ __launch_bounds__(384) void fc_tail_kernel(
    const float* __restrict__ partial,  // [8,512,256]
    const float* __restrict__ fc1_b,    // [256]
    const float* __restrict__ l,        // [512,8]
    const float* __restrict__ fc2_w,    // [128,8]
    const float* __restrict__ fc2_b,    // [128]
    const float* __restrict__ fc3_w,    // [384,256]
    const float* __restrict__ fc3_b,    // [384]
    const float* __restrict__ fc4_w,    // [384,128]
    const float* __restrict__ fc4_b,    // [384]
    float* __restrict__ phi_out,        // [512,256]
    float* __restrict__ g_t)            // [512,384]
{
    __shared__ float ph_s[2 * 256];
    __shared__ float lo_s[2 * 128];
    int bt = blockIdx.x, t = threadIdx.x;

    for (int idx = t; idx < 512; idx += 384) {
        int bb = idx >> 8, ch = idx & 255;
        size_t gidx = ((size_t)(bt * 2 + bb)) * 256 + ch;
        float s = fc1_b[ch];
        #pragma unroll
        for (int kc = 0; kc < 8; ++kc) s += partial[(size_t)kc * 131072 + gidx];
        s = fmaxf(s, 0.0f);
        ph_s[idx] = s;
        phi_out[gidx] = s;
    }
    for (int idx = t; idx < 256; idx += 384) {
        int bb = idx >> 7, ch = idx & 127;
        int b = bt * 2 + bb;
        float a = fc2_b[ch];
        const float* lb = l + b * 8;
        const float* wr = fc2_w + ch * 8;
        #pragma unroll
        for (int m = 0; m < 8; ++m) a += lb[m] * wr[m];
        lo_s[idx] = fmaxf(a, 0.0f);
    }
    __syncthreads();

    float base = fc3_b[t] + fc4_b[t];
    float acc[2] = {base, base};
    const float4* w3 = (const float4*)(fc3_w + (size_t)t * 256);
    for (int k4 = 0; k4 < 64; ++k4) {
        float4 wv = w3[k4];
        #pragma unroll
        for (int bb = 0; bb < 2; ++bb) {
            float4 iv = *(const float4*)&ph_s[bb * 256 + k4 * 4];
            acc[bb] += wv.x*iv.x + wv.y*iv.y + wv.z*iv.z + wv.w*iv.w;
        }
    }
    const float4* w4 = (const float4*)(fc4_w + (size_t)t * 128);
    for (int k4 = 0; k4 < 32; ++k4) {
        float4 wv = w4[k4];
        #pragma unroll
        for (int bb = 0; bb < 2; ++bb) {
            float4 iv = *(const float4*)&lo_s[bb * 128 + k4 * 4];
            acc[bb] += wv.x*iv.x + wv.y*iv.y + wv.z*iv.z + wv.w*iv.w;
        }
    }
    #pragma unroll
    for (int bb = 0; bb < 2; ++bb)
        g_t[((size_t)bt * 2 + bb) * 384 + t] = fmaxf(acc[bb], 0.0f);
}

extern "C" void kernel_launch(void* const* d_in, const int* in_sizes, int n_in,
                              void* d_out, int out_size, void* d_ws, size_t ws_size,
                              hipStream_t stream) {
    const float* x   = (const float*)d_in[0];
    const float* l   = (const float*)d_in[1];
    const float* c1w = (const float*)d_in[2];
    const float* c1b = (const float*)d_in[3];
    const float* c2w = (const float*)d_in[4];
    const float* c2b = (const float*)d_in[5];
    const float* f1w = (const float*)d_in[6];
    const float* f1b = (const float*)d_in[7];
    const float* f2w = (const float*)d_in[8];
    const float* f2b = (const float*)d_in[9];
    const float* f3w = (const float*)d_in[10];
    const float* f3b = (const float*)d_in[11];
    const float* f4w = (const float*)d_in[12];
    const float* f4b = (const float*)d_in[13];

    float* out       = (float*)d_out;
    float* phi_out_p = out + PHI_OUT_OFF;
    float* gt_p      = out + GT_OFF;
    float* bbox_p    = out + BBOX_OFF;

    float* ws      = (float*)d_ws;
    float* h2      = ws + WS_H2;
    float* partial = ws + WS_PART;
    float* w2t     = ws + WS_W2T;
    float* w1t     = ws + WS_W1T;

    repack_kernel<<<96, 256, 0, stream>>>(c2w, c1w, w2t, w1t);
    glimpse_conv_kernel<<<512, 256, 0, stream>>>(x, l, w1t, c1b, w2t, c2b,
                                                 h2, bbox_p);
    fc1_partial_kernel<<<dim3(64, 8), 256, 0, stream>>>(h2, f1w, partial);
    fc_tail_kernel<<<256, 384, 0, stream>>>(partial, f1b, l, f2w, f2b,
                                            f3w, f3b, f4w, f4b,
                                            phi_out_p, gt_p);
}